// Round 7
// baseline (125.166 us; speedup 1.0000x reference)
//
#include <hip/hip_runtime.h>
#include <hip/hip_bf16.h>

#define B_  8
#define CI_ 32
#define CO_ 64
#define F_  4
#define H_  64
#define W_  64

#define SENT_ 0x5EC0FFEEu   // != 0xAAAAAAAA poison, != 0

// Single regular launch, 512 blocks x 256 threads (<=2 blocks/CU -> all 512
// co-resident; spin barrier is capacity-safe). No cooperative launch.
//
// Blocks 0..255 (j = b*CI+i): reduce v-plane j (4 float4/thread, coalesced):
//   iv[j]  = dx^2 * sum_{h,w} wgt * v[j,h,w]
//   T[j,d] = dx^2 * sum_{h,w} wgt * vc[h,w,d] * v[j,h,w]
// then __threadfence (agent release: wbl2) + agent-scope release-store of a
// sentinel into flag[j]. Sentinel scheme needs no assumption about d_ws's
// initial contents (0xAA poison or anything else).
//
// ALL 512 blocks: thread t spins (acquire, agent scope -> buffer_inv) on
// flag[t] until sentinel, __syncthreads, then compute plane bo=blockIdx.x:
//   Sx_d = sum_{f,i} Wx[f,o,i,d]*iv[b,i], C = sum_{f,i,d} Wy[f,o,i,d]*T[b,i,d]
//   out[b,o,h,w] = tc[h,w,0]*Sx0 + tc[h,w,1]*Sx1 + C   (1024 float4 stores)
__global__ __launch_bounds__(256) void k_all(
    const float* __restrict__ v, const float* __restrict__ vc,
    const float* __restrict__ tc, const float* __restrict__ Wx,
    const float* __restrict__ Wy, unsigned* __restrict__ flag,
    float* __restrict__ iv, float* __restrict__ T,
    float* __restrict__ out) {
  const int blk = blockIdx.x;        // 0 .. 511
  const int tid = threadIdx.x;       // 0 .. 255
  const int wave = tid >> 6;
  const int lane = tid & 63;

  __shared__ float red[4][3];
  __shared__ float bc[3];

  // ---------------- Phase 1: blocks 0..255 reduce one (b,i) plane ----------
  if (blk < B_ * CI_) {
#define GW_(w) ((((w) == 0) || ((w) == W_ - 1)) ? 0.5f : 1.0f)
    const int w4  = tid & 15;        // float4 column, invariant over r
    const int wsc = w4 * 4;
    const float4 wg = make_float4(GW_(wsc), GW_(wsc + 1), GW_(wsc + 2), GW_(wsc + 3));
    const float cx0 = vc[2 * wsc],       cx1 = vc[2 * (wsc + 1)];
    const float cx2 = vc[2 * (wsc + 2)], cx3 = vc[2 * (wsc + 3)];

    const float4* vp = (const float4*)(v + (size_t)blk * (H_ * W_));
    float s0 = 0.f, s1 = 0.f, s2 = 0.f;
#pragma unroll
    for (int r = 0; r < 4; ++r) {
      int p4 = r * 256 + tid;        // 0..1023, coalesced
      int h  = p4 >> 4;
      float4 a = vp[p4];
      float rs0 = a.x * wg.x + a.y * wg.y + a.z * wg.z + a.w * wg.w;
      float rs1 = a.x * wg.x * cx0 + a.y * wg.y * cx1
                + a.z * wg.z * cx2 + a.w * wg.w * cx3;
      float wh = ((h == 0) || (h == H_ - 1)) ? 0.5f : 1.0f;
      float cy = vc[h * (W_ * 2) + 1];
      s0 += wh * rs0;
      s1 += wh * rs1;
      s2 += (wh * cy) * rs0;
    }
    for (int off = 32; off > 0; off >>= 1) {
      s0 += __shfl_down(s0, off, 64);
      s1 += __shfl_down(s1, off, 64);
      s2 += __shfl_down(s2, off, 64);
    }
    if (lane == 0) {
      red[wave][0] = s0; red[wave][1] = s1; red[wave][2] = s2;
    }
    __syncthreads();
    if (tid == 0) {
      float t0 = red[0][0] + red[1][0] + red[2][0] + red[3][0];
      float t1 = red[0][1] + red[1][1] + red[2][1] + red[3][1];
      float t2 = red[0][2] + red[1][2] + red[2][2] + red[3][2];
      float dx = vc[2] - vc[0];      // v_coords[0,1,0] - v_coords[0,0,0]
      float sc = dx * dx;
      iv[blk]        = t0 * sc;
      T[2 * blk]     = t1 * sc;
      T[2 * blk + 1] = t2 * sc;
      __threadfence();               // agent release: L2 writeback
      __hip_atomic_store(&flag[blk], SENT_, __ATOMIC_RELEASE,
                         __HIP_MEMORY_SCOPE_AGENT);
    }
  }

  // ---------------- Device-wide barrier via sentinel flags -----------------
  // thread t watches flag[t]; acquire at agent scope invalidates L1/L2 so
  // post-barrier reads of iv/T see the producers' data.
  while (__hip_atomic_load(&flag[tid], __ATOMIC_ACQUIRE,
                           __HIP_MEMORY_SCOPE_AGENT) != SENT_) {
    __builtin_amdgcn_s_sleep(2);
  }
  __syncthreads();

  // ---------------- Phase 2: coefficients + plane write --------------------
  const int bo = blk;                // b*CO + o
  const int b  = bo >> 6;            // CO = 64
  const int o  = bo & 63;

  float sx0 = 0.f, sx1 = 0.f, c = 0.f;
  if (tid < CI_ * F_) {              // 128 active (i,f) terms
    int i = tid & (CI_ - 1);
    int f = tid >> 5;
    float ivbi = iv[b * CI_ + i];
    float t0 = T[(b * CI_ + i) * 2];
    float t1 = T[(b * CI_ + i) * 2 + 1];
    int base = ((f * CO_ + o) * CI_ + i) * 2;
    float2 wx = *(const float2*)(Wx + base);
    float2 wy = *(const float2*)(Wy + base);
    sx0 = wx.x * ivbi;
    sx1 = wx.y * ivbi;
    c   = wy.x * t0 + wy.y * t1;
  }
  for (int off = 32; off > 0; off >>= 1) {
    sx0 += __shfl_down(sx0, off, 64);
    sx1 += __shfl_down(sx1, off, 64);
    c   += __shfl_down(c,   off, 64);
  }
  __syncthreads();                   // red[] reuse: phase-1 reads done
  if (wave < 2 && lane == 0) {
    red[wave][0] = sx0; red[wave][1] = sx1; red[wave][2] = c;
  }
  __syncthreads();
  if (tid == 0) {
    bc[0] = red[0][0] + red[1][0];
    bc[1] = red[0][1] + red[1][1];
    bc[2] = red[0][2] + red[1][2];
  }
  __syncthreads();
  const float SX0 = bc[0], SX1 = bc[1], C = bc[2];

  float4* outp = (float4*)out + (size_t)bo * 1024;
#pragma unroll
  for (int r = 0; r < 4; ++r) {
    int p4 = r * 256 + tid;          // 0..1023
    int h  = p4 >> 4;                // 16 float4 per row
    int wq = p4 & 15;
    const float4* tcp = (const float4*)(tc + (size_t)(h * W_ + wq * 4) * 2);
    float4 t0v = tcp[0];             // gx0, gy0, gx1, gy1
    float4 t1v = tcp[1];             // gx2, gy2, gx3, gy3
    float4 rr;
    rr.x = t0v.x * SX0 + t0v.y * SX1 + C;
    rr.y = t0v.z * SX0 + t0v.w * SX1 + C;
    rr.z = t1v.x * SX0 + t1v.y * SX1 + C;
    rr.w = t1v.z * SX0 + t1v.w * SX1 + C;
    outp[p4] = rr;
  }
}

extern "C" void kernel_launch(void* const* d_in, const int* in_sizes, int n_in,
                              void* d_out, int out_size, void* d_ws, size_t ws_size,
                              hipStream_t stream) {
  const float* v  = (const float*)d_in[0];   // [B,CI,H,W]
  const float* vc = (const float*)d_in[1];   // [H,W,2]
  const float* tc = (const float*)d_in[2];   // [H,W,2]
  const float* Wx = (const float*)d_in[3];   // [F,CO,CI,2]
  const float* Wy = (const float*)d_in[4];   // [F,CO,CI,2]
  float* out = (float*)d_out;                // [B,CO,H,W]

  // ws layout: flag[256] (uint) | iv[256] (float) | T[512] (float)
  unsigned* flag = (unsigned*)d_ws;
  float* iv = (float*)d_ws + 256;
  float* T  = iv + B_ * CI_;

  k_all<<<2 * B_ * CI_, 256, 0, stream>>>(v, vc, tc, Wx, Wy, flag, iv, T, out);
}

// Round 8
// 75.463 us; speedup vs baseline: 1.6586x; 1.6586x over previous
//
#include <hip/hip_runtime.h>
#include <hip/hip_bf16.h>

#define B_  8
#define CI_ 32
#define CO_ 64
#define F_  4
#define H_  64
#define W_  64

// Single regular launch, 64 blocks x 1024 threads, no device-wide sync.
// Block blk = (b, o-octet): b = blk>>3, o0 = (blk&7)*8 (planes o0..o0+7).
//
// Phase A (8x redundant across the 8 blocks sharing b — 32 MB aggregate
// L2/L3 traffic, ~3 us): reduce v[b,:,:,:] (512 KB) into ivT[i][3]:
//   ivT[i][0] = dx^2 * sum_{h,w} wgt * v[b,i,h,w]
//   ivT[i][1] = dx^2 * sum_{h,w} wgt * cx(w) * v[b,i,h,w]
//   ivT[i][2] = dx^2 * sum_{h,w} wgt * cy(h) * v[b,i,h,w]
// (wgt = trapezoid weights, 0.5 at boundary rows/cols; verified in R5/R6.)
// 32 threads per channel, 32 independent float4 loads each.
//
// Phase B: 8 o's x 128 (i,f) terms = 1024 threads exactly:
//   Sx_d[o] = sum_{f,i} Wx[f,o,i,d]*ivT[i][0]
//   C[o]    = sum_{f,i} (Wy[f,o,i,0]*ivT[i][1] + Wy[f,o,i,1]*ivT[i][2])
//
// Phase C: thread t owns pixel-quad p4 = t in ALL 8 planes: 2 tc loads,
// 8 coalesced float4 stores:  out[b,o,h,w] = gx*Sx0 + gy*Sx1 + C.
__global__ __launch_bounds__(1024) void k_all(
    const float* __restrict__ v, const float* __restrict__ vc,
    const float* __restrict__ tc, const float* __restrict__ Wx,
    const float* __restrict__ Wy, float* __restrict__ out) {
  const int blk = blockIdx.x;        // 0 .. 63
  const int tid = threadIdx.x;       // 0 .. 1023
  const int b   = blk >> 3;
  const int o0  = (blk & 7) * 8;

  __shared__ float ivT[CI_][3];      // stride 3: conflict-free mod 32
  __shared__ float red[16][3];
  __shared__ float bc[8][3];

  // ---------------- Phase A ----------------
  {
    const int i   = tid >> 5;        // channel 0..31
    const int sub = tid & 31;        // 32 threads/channel
    const int w4  = sub & 15;        // fixed float4-column (32 % 16 == 0)
    const int hb  = sub >> 4;        // h parity: h = 2r + hb

#define GW_(w) ((((w) == 0) || ((w) == W_ - 1)) ? 0.5f : 1.0f)
    const int wsc = w4 * 4;
    const float4 wg = make_float4(GW_(wsc), GW_(wsc + 1), GW_(wsc + 2), GW_(wsc + 3));
    const float4 wc = make_float4(wg.x * vc[2 * wsc],       wg.y * vc[2 * (wsc + 1)],
                                  wg.z * vc[2 * (wsc + 2)], wg.w * vc[2 * (wsc + 3)]);

    const float4* vrow = (const float4*)(v + (size_t)(b * CI_ + i) * (H_ * W_));
    float s0 = 0.f, s1 = 0.f, s2 = 0.f;
#pragma unroll 8
    for (int r = 0; r < 32; ++r) {
      int p4 = r * 32 + sub;         // covers 0..1023 once per channel
      int h  = 2 * r + hb;
      float4 a = vrow[p4];
      float rs0 = a.x * wg.x + a.y * wg.y + a.z * wg.z + a.w * wg.w;
      float rs1 = a.x * wc.x + a.y * wc.y + a.z * wc.z + a.w * wc.w;
      float wh = ((h == 0) || (h == H_ - 1)) ? 0.5f : 1.0f;
      float cy = vc[h * (W_ * 2) + 1];
      s0 += wh * rs0;
      s1 += wh * rs1;
      s2 += (wh * cy) * rs0;
    }
    // reduce across the 32 threads of this channel (half-wave)
    for (int m = 1; m < 32; m <<= 1) {
      s0 += __shfl_xor(s0, m, 64);
      s1 += __shfl_xor(s1, m, 64);
      s2 += __shfl_xor(s2, m, 64);
    }
    if (sub == 0) {
      float dx = vc[2] - vc[0];      // v_coords[0,1,0] - v_coords[0,0,0]
      float sc = dx * dx;
      ivT[i][0] = s0 * sc;
      ivT[i][1] = s1 * sc;
      ivT[i][2] = s2 * sc;
    }
  }
  __syncthreads();

  // ---------------- Phase B ----------------
  {
    const int ol  = tid >> 7;        // local o 0..7 (2 waves per o)
    const int rem = tid & 127;
    const int i   = rem & 31;
    const int f   = rem >> 5;        // 0..3
    const int o   = o0 + ol;
    float ivi = ivT[i][0];
    float t0  = ivT[i][1];
    float t1  = ivT[i][2];
    int base = ((f * CO_ + o) * CI_ + i) * 2;
    float2 wx = *(const float2*)(Wx + base);
    float2 wy = *(const float2*)(Wy + base);
    float sx0 = wx.x * ivi;
    float sx1 = wx.y * ivi;
    float c   = wy.x * t0 + wy.y * t1;
    for (int off = 32; off > 0; off >>= 1) {
      sx0 += __shfl_down(sx0, off, 64);
      sx1 += __shfl_down(sx1, off, 64);
      c   += __shfl_down(c,   off, 64);
    }
    const int wave = tid >> 6;       // 0..15; waves 2k,2k+1 belong to o-local k
    if ((tid & 63) == 0) {
      red[wave][0] = sx0; red[wave][1] = sx1; red[wave][2] = c;
    }
  }
  __syncthreads();
  if (tid < 8) {
    bc[tid][0] = red[2 * tid][0] + red[2 * tid + 1][0];
    bc[tid][1] = red[2 * tid][1] + red[2 * tid + 1][1];
    bc[tid][2] = red[2 * tid][2] + red[2 * tid + 1][2];
  }
  __syncthreads();

  // ---------------- Phase C ----------------
  {
    const int p4 = tid;              // 0..1023, same quad in all 8 planes
    const int h  = p4 >> 4;          // 16 float4 per row
    const int wq = p4 & 15;
    const float4* tcp = (const float4*)(tc + (size_t)(h * W_ + wq * 4) * 2);
    const float4 t0v = tcp[0];       // gx0, gy0, gx1, gy1
    const float4 t1v = tcp[1];       // gx2, gy2, gx3, gy3
    float4* outp = (float4*)out + (size_t)(b * CO_ + o0) * 1024 + p4;
#pragma unroll
    for (int k = 0; k < 8; ++k) {
      const float S0 = bc[k][0], S1 = bc[k][1], Cc = bc[k][2];
      float4 rr;
      rr.x = t0v.x * S0 + t0v.y * S1 + Cc;
      rr.y = t0v.z * S0 + t0v.w * S1 + Cc;
      rr.z = t1v.x * S0 + t1v.y * S1 + Cc;
      rr.w = t1v.z * S0 + t1v.w * S1 + Cc;
      outp[(size_t)k * 1024] = rr;
    }
  }
}

extern "C" void kernel_launch(void* const* d_in, const int* in_sizes, int n_in,
                              void* d_out, int out_size, void* d_ws, size_t ws_size,
                              hipStream_t stream) {
  const float* v  = (const float*)d_in[0];   // [B,CI,H,W]
  const float* vc = (const float*)d_in[1];   // [H,W,2]
  const float* tc = (const float*)d_in[2];   // [H,W,2]
  const float* Wx = (const float*)d_in[3];   // [F,CO,CI,2]
  const float* Wy = (const float*)d_in[4];   // [F,CO,CI,2]
  float* out = (float*)d_out;                // [B,CO,H,W]

  k_all<<<B_ * (CO_ / 8), 1024, 0, stream>>>(v, vc, tc, Wx, Wy, out);
}

// Round 9
// 69.002 us; speedup vs baseline: 1.8139x; 1.0936x over previous
//
#include <hip/hip_runtime.h>
#include <hip/hip_bf16.h>

#define B_  8
#define CI_ 32
#define CO_ 64
#define F_  4
#define H_  64
#define W_  64

// Kernel 1 (R6-proven): one block per (b,i), 1024 threads, ONE float4 of v
// per thread (1024 x 16B = the full 64x64 plane). Computes
//   iv[b,i]   = dx^2 * sum_{h,w} wgt * v[b,i,h,w]
//   T[b,i,d]  = dx^2 * sum_{h,w} wgt * vc[h,w,d] * v[b,i,h,w]
// wgt = trapezoid weights (0.5 at h/w boundaries). Fully coalesced.
__global__ __launch_bounds__(1024) void k_reduce(
    const float* __restrict__ v, const float* __restrict__ vc,
    float* __restrict__ iv, float* __restrict__ T) {
  const int bi  = blockIdx.x;        // 0 .. B*CI-1
  const int tid = threadIdx.x;       // 0 .. 1023
  const int h   = tid >> 4;          // 16 float4 per row
  const int w4  = tid & 15;

#define GW_(w) ((((w) == 0) || ((w) == W_ - 1)) ? 0.5f : 1.0f)
  const int wsc = w4 * 4;
  const float4 wg = make_float4(GW_(wsc), GW_(wsc + 1), GW_(wsc + 2), GW_(wsc + 3));
  const float cx0 = vc[2 * wsc],       cx1 = vc[2 * (wsc + 1)];
  const float cx2 = vc[2 * (wsc + 2)], cx3 = vc[2 * (wsc + 3)];
  const float cy  = vc[h * (W_ * 2) + 1];
  const float wh  = ((h == 0) || (h == H_ - 1)) ? 0.5f : 1.0f;

  float4 a = ((const float4*)(v + (size_t)bi * (H_ * W_)))[tid];

  float rs0 = a.x * wg.x + a.y * wg.y + a.z * wg.z + a.w * wg.w;
  float rs1 = a.x * wg.x * cx0 + a.y * wg.y * cx1 + a.z * wg.z * cx2 + a.w * wg.w * cx3;
  float s0 = wh * rs0;
  float s1 = wh * rs1;
  float s2 = wh * cy * rs0;

  for (int off = 32; off > 0; off >>= 1) {
    s0 += __shfl_down(s0, off, 64);
    s1 += __shfl_down(s1, off, 64);
    s2 += __shfl_down(s2, off, 64);
  }
  __shared__ float red[16][3];
  const int wave = tid >> 6;
  if ((tid & 63) == 0) {
    red[wave][0] = s0; red[wave][1] = s1; red[wave][2] = s2;
  }
  __syncthreads();
  if (tid < 16) {                    // all in wave 0
    float t0 = red[tid][0], t1 = red[tid][1], t2 = red[tid][2];
    for (int off = 8; off > 0; off >>= 1) {
      t0 += __shfl_down(t0, off, 64);
      t1 += __shfl_down(t1, off, 64);
      t2 += __shfl_down(t2, off, 64);
    }
    if (tid == 0) {
      float dx = vc[2] - vc[0];      // v_coords[0,1,0] - v_coords[0,0,0]
      float sc = dx * dx;
      iv[bi]        = t0 * sc;
      T[2 * bi]     = t1 * sc;
      T[2 * bi + 1] = t2 * sc;
    }
  }
}

// Kernel 2: ONE block per (b,o) plane, 1024 threads. Coefficients computed
// once per plane (was 4x in R6), then each thread writes exactly one float4:
//   Sx_d = sum_{f,i} Wx[f,o,i,d]*iv[b,i]
//   C    = sum_{f,i,d} Wy[f,o,i,d]*T[b,i,d]
//   out[b,o,h,w] = tc[h,w,0]*Sx0 + tc[h,w,1]*Sx1 + C
__global__ __launch_bounds__(1024) void k_out_fused(
    const float* __restrict__ tc, const float* __restrict__ Wx,
    const float* __restrict__ Wy, const float* __restrict__ iv,
    const float* __restrict__ T, float* __restrict__ out) {
  const int bo  = blockIdx.x;        // b*CO + o
  const int tid = threadIdx.x;       // 0 .. 1023
  const int b   = bo >> 6;           // CO = 64
  const int o   = bo & 63;

  __shared__ float red[2][3];
  __shared__ float bc[3];

  // coefficient phase: 128 active threads (2 waves), one (i,f) term each
  if (tid < CI_ * F_) {
    int i = tid & (CI_ - 1);
    int f = tid >> 5;
    float ivbi = iv[b * CI_ + i];
    float t0 = T[(b * CI_ + i) * 2];
    float t1 = T[(b * CI_ + i) * 2 + 1];
    int base = ((f * CO_ + o) * CI_ + i) * 2;
    float2 wx = *(const float2*)(Wx + base);
    float2 wy = *(const float2*)(Wy + base);
    float sx0 = wx.x * ivbi;
    float sx1 = wx.y * ivbi;
    float c   = wy.x * t0 + wy.y * t1;
    for (int off = 32; off > 0; off >>= 1) {
      sx0 += __shfl_down(sx0, off, 64);
      sx1 += __shfl_down(sx1, off, 64);
      c   += __shfl_down(c,   off, 64);
    }
    if ((tid & 63) == 0) {
      int wave = tid >> 6;           // 0 or 1
      red[wave][0] = sx0; red[wave][1] = sx1; red[wave][2] = c;
    }
  }
  __syncthreads();
  if (tid == 0) {
    bc[0] = red[0][0] + red[1][0];
    bc[1] = red[0][1] + red[1][1];
    bc[2] = red[0][2] + red[1][2];
  }
  __syncthreads();
  const float SX0 = bc[0], SX1 = bc[1], C = bc[2];

  // write phase: thread tid owns float4 p4 = tid of this plane
  const int p4 = tid;                // 0..1023
  const int h  = p4 >> 4;            // 16 float4 per row
  const int wq = p4 & 15;
  const float4* tcp = (const float4*)(tc + (size_t)(h * W_ + wq * 4) * 2);
  float4 t0v = tcp[0];               // gx0, gy0, gx1, gy1
  float4 t1v = tcp[1];               // gx2, gy2, gx3, gy3

  float4 r;
  r.x = t0v.x * SX0 + t0v.y * SX1 + C;
  r.y = t0v.z * SX0 + t0v.w * SX1 + C;
  r.z = t1v.x * SX0 + t1v.y * SX1 + C;
  r.w = t1v.z * SX0 + t1v.w * SX1 + C;

  ((float4*)out)[(size_t)bo * 1024 + p4] = r;
}

extern "C" void kernel_launch(void* const* d_in, const int* in_sizes, int n_in,
                              void* d_out, int out_size, void* d_ws, size_t ws_size,
                              hipStream_t stream) {
  const float* v  = (const float*)d_in[0];   // [B,CI,H,W]
  const float* vc = (const float*)d_in[1];   // [H,W,2]
  const float* tc = (const float*)d_in[2];   // [H,W,2]
  const float* Wx = (const float*)d_in[3];   // [F,CO,CI,2]
  const float* Wy = (const float*)d_in[4];   // [F,CO,CI,2]
  float* out = (float*)d_out;                // [B,CO,H,W]

  // workspace layout (floats): iv[256] | T[512]
  float* iv = (float*)d_ws;
  float* T  = iv + B_ * CI_;

  k_reduce<<<B_ * CI_, 1024, 0, stream>>>(v, vc, iv, T);
  k_out_fused<<<B_ * CO_, 1024, 0, stream>>>(tc, Wx, Wy, iv, T, out);
}